// Round 1
// baseline (3506.621 us; speedup 1.0000x reference)
//
#include <hip/hip_runtime.h>
#include <cstdint>
#include <cstddef>

// ---------------- constants ----------------
constexpr int kB = 16, kL = 2048, kD = 256, kA = 128, kN = 256, kC = 128;
constexpr int kH = 128, kG = 384, kGN = 768;               // GRU: 3H=384, both dirs = 768
constexpr int kT1 = 2046, kT2 = 2045, kT3 = 2044, kTT = 6135;
constexpr float kEPS = 1e-5f;

// ---------------- workspace layout (floats) ----------------
constexpr size_t OFF_XE   = 0;                                   // [B*L, 256]
constexpr size_t OFF_GI   = OFF_XE + (size_t)kB*kL*kD;           // [B*L, 768]  (U overlays after GRU)
constexpr size_t OFF_FHAT = OFF_GI + (size_t)kB*kL*kGN;          // [B,N,D]
constexpr size_t OFF_UF   = OFF_FHAT + (size_t)kB*kN*kD;         // [B,N,D]
constexpr size_t OFF_EFFW = OFF_UF + (size_t)kB*kN*kD;           // [12,256,256] folded conv weights
constexpr size_t OFF_EFFB = OFF_EFFW + (size_t)12*kD*kD;         // [3,256]
constexpr size_t OFF_W6AT = OFF_EFFB + (size_t)3*kD;             // [256,256]
constexpr size_t OFF_W6BT = OFF_W6AT + (size_t)kD*kD;
constexpr size_t OFF_W1T  = OFF_W6BT + (size_t)kD*kD;
constexpr size_t OFF_W2T  = OFF_W1T + (size_t)kD*kD;
constexpr size_t OFF_W3T  = OFF_W2T + (size_t)kD*kD;
constexpr size_t OFF_W4T  = OFF_W3T + (size_t)kD*kD;
constexpr size_t OFF_DHAT = OFF_W4T + (size_t)kD*kD;             // [A,D]
constexpr size_t OFF_P1   = OFF_DHAT + (size_t)kA*kD;
constexpr size_t OFF_P2   = OFF_P1 + (size_t)kA*kD;
constexpr size_t OFF_P3   = OFF_P2 + (size_t)kA*kD;
constexpr size_t OFF_RS   = OFF_P3 + (size_t)kA*kD;              // [A]
constexpr size_t OFF_CS   = OFF_RS + kA;                         // [A]
constexpr size_t OFF_H1   = OFF_CS + kA;                         // [B,256]
constexpr size_t OFF_C1   = OFF_H1 + (size_t)kB*kD;
constexpr size_t OFF_HFv  = OFF_C1 + (size_t)kB*kD;
constexpr size_t OFF_C2   = OFF_HFv + (size_t)kB*kD;
constexpr size_t OFF_HT   = OFF_C2 + (size_t)kB*kD;
constexpr size_t OFF_SCF  = OFF_HT + (size_t)kB*kD;              // [B,N]
constexpr size_t OFF_SC   = OFF_SCF + (size_t)kB*kN;             // [B,6135]
constexpr size_t OFF_PART = OFF_SC + (size_t)kB*kTT;             // [48,B,256]
// total ~37.3M floats = ~149 MB

// ---------------- small helpers ----------------
__device__ __forceinline__ float sigm(float x) { return 1.f / (1.f + __expf(-x)); }
__device__ __forceinline__ float tanh_fast(float x) {
  x = fminf(15.f, fmaxf(-15.f, x));
  float e2 = __expf(2.f * x);
  return (e2 - 1.f) / (e2 + 1.f);
}

// dst[i*256 + d] = src[d*stride + i]   (256x256 transpose)
__global__ void k_transpose(float* dst, const float* src, int stride) {
  int i = blockIdx.x, d = threadIdx.x;
  dst[i * kD + d] = src[(size_t)d * stride + i];
}

__global__ void k_rowcol(const float* DDm, float* rs, float* cs) {
  int a = threadIdx.x; // 128
  float r = 0.f, c = 0.f;
  for (int j = 0; j < kA; ++j) { r += DDm[a * kA + j]; c += DDm[j * kA + a]; }
  rs[a] = r; cs[a] = c;
}

// P{1,2,3}[a][d] = sum_i Dm[a][i]*W{1,2,3}T[i][d]
__global__ void k_proj3(const float* Dm, const float* W1T, const float* W2T, const float* W3T,
                        float* P1, float* P2, float* P3) {
  __shared__ float row[kD];
  int a = blockIdx.x, d = threadIdx.x;
  row[d] = Dm[a * kD + d];
  __syncthreads();
  float s1 = 0, s2 = 0, s3 = 0;
  for (int i = 0; i < kD; ++i) {
    float v = row[i];
    s1 = fmaf(v, W1T[i * kD + d], s1);
    s2 = fmaf(v, W2T[i * kD + d], s2);
    s3 = fmaf(v, W3T[i * kD + d], s3);
  }
  P1[a * kD + d] = s1; P2[a * kD + d] = s2; P3[a * kD + d] = s3;
}

__global__ void k_dhat(const float* DDm, const float* P1, const float* P2, const float* P3,
                       const float* rs, const float* cs, float* Dhat) {
  __shared__ float drow[kA], dcol[kA];
  int a = blockIdx.x, d = threadIdx.x;
  if (d < kA) { drow[d] = DDm[a * kA + d]; dcol[d] = DDm[d * kA + a]; }
  __syncthreads();
  float q2 = 0, q3 = 0;
  for (int j = 0; j < kA; ++j) {
    q2 = fmaf(drow[j], P2[j * kD + d], q2);
    q3 = fmaf(dcol[j], P3[j * kD + d], q3);
  }
  float v = P1[a * kD + d] + q2 / (rs[a] + kEPS) + q3 / (cs[a] + kEPS);
  Dhat[a * kD + d] = v > 0.f ? v : 0.f;
}

// F_hat[b,n,d] = relu(Fm@W4.T + (D_F^T on a)·Dhat / den) * mask ; block = (nchunk16, b)
__global__ void k_fhat(const int* nodes, const float* nmask, const float* eemb,
                       const float* DF, const float* W4T, const float* Dhat, float* Fhat) {
  int b = blockIdx.y, n0 = blockIdx.x * 16, d = threadIdx.x;
  __shared__ float fm[16][kD];
  __shared__ float dc[kA][16];
  __shared__ float den[16], msk[16];
  for (int r = 0; r < 16; ++r) {
    int idx = nodes[b * kN + n0 + r];
    float m = nmask[b * kN + n0 + r];
    fm[r][d] = eemb[(size_t)idx * kD + d] * m;
    if (d == 0) msk[r] = m;
  }
  for (int q = 0; q < 8; ++q) {
    int e = q * 256 + d;
    int aa = e >> 4, nn = e & 15;
    dc[aa][nn] = DF[(size_t)b * kA * kN + (size_t)aa * kN + n0 + nn];
  }
  __syncthreads();
  if (d < 16) {
    float s = 0.f;
    for (int aa = 0; aa < kA; ++aa) s += dc[aa][d];
    den[d] = s;
  }
  __syncthreads();
  float a1[16], a2[16];
#pragma unroll
  for (int n = 0; n < 16; ++n) { a1[n] = 0.f; a2[n] = 0.f; }
  for (int i = 0; i < kD; ++i) {
    float w = W4T[i * kD + d];
#pragma unroll
    for (int n = 0; n < 16; ++n) a1[n] = fmaf(fm[n][i], w, a1[n]);
  }
  for (int aa = 0; aa < kA; ++aa) {
    float w = Dhat[aa * kD + d];
#pragma unroll
    for (int n = 0; n < 16; ++n) a2[n] = fmaf(dc[aa][n], w, a2[n]);
  }
#pragma unroll
  for (int n = 0; n < 16; ++n) {
    float v = a1[n] + a2[n] / (den[n] + kEPS);
    v = v > 0.f ? v : 0.f;
    Fhat[((size_t)b * kN + n0 + n) * kD + d] = v * msk[n];
  }
}

// xe gather: 16 rows per block
__global__ void k_xe(const int* x, const float* wemb, float* xe) {
  int r0 = blockIdx.x * 16;
  int t = threadIdx.x;
  int rr = t >> 6, c = t & 63;
  for (int s = 0; s < 4; ++s) {
    int r = r0 + rr + s * 4;
    int idx = x[r];
    ((float4*)(xe + (size_t)r * kD))[c] = ((const float4*)(wemb + (size_t)idx * kD))[c];
  }
}

// gi[32768 x 768] = xe[32768x256] @ [wih_f;wih_b]^T + bias
__global__ __launch_bounds__(256) void k_gemm_gi(const float* Aa, const float* wf, const float* wb,
                                                 const float* bf, const float* bb, float* Cc) {
  __shared__ alignas(16) float As[64][68];
  __shared__ alignas(16) float Bs[64][68];
  int m0 = blockIdx.x * 64, n0 = blockIdx.y * 64;
  int tid = threadIdx.x;
  int tx = tid & 15, ty = tid >> 4;
  float acc[4][4];
#pragma unroll
  for (int q = 0; q < 4; ++q)
#pragma unroll
    for (int p = 0; p < 4; ++p) acc[q][p] = 0.f;
  for (int kk = 0; kk < 256; kk += 64) {
    {
      int r = tid >> 2, c0 = (tid & 3) * 16;
      const float* src = Aa + (size_t)(m0 + r) * kD + kk + c0;
      float4 v0 = ((const float4*)src)[0], v1 = ((const float4*)src)[1];
      float4 v2 = ((const float4*)src)[2], v3 = ((const float4*)src)[3];
      *((float4*)&As[r][c0])      = v0; *((float4*)&As[r][c0 + 4])  = v1;
      *((float4*)&As[r][c0 + 8])  = v2; *((float4*)&As[r][c0 + 12]) = v3;
      int n = n0 + r;
      const float* wsrc = (n < kG) ? (wf + (size_t)n * kD) : (wb + (size_t)(n - kG) * kD);
      wsrc += kk + c0;
      float4 w0 = ((const float4*)wsrc)[0], w1 = ((const float4*)wsrc)[1];
      float4 w2 = ((const float4*)wsrc)[2], w3 = ((const float4*)wsrc)[3];
      *((float4*)&Bs[r][c0])      = w0; *((float4*)&Bs[r][c0 + 4])  = w1;
      *((float4*)&Bs[r][c0 + 8])  = w2; *((float4*)&Bs[r][c0 + 12]) = w3;
    }
    __syncthreads();
#pragma unroll 4
    for (int k4 = 0; k4 < 16; ++k4) {
      float4 av[4], bv[4];
#pragma unroll
      for (int q = 0; q < 4; ++q) av[q] = *(const float4*)&As[ty * 4 + q][k4 * 4];
#pragma unroll
      for (int p = 0; p < 4; ++p) bv[p] = *(const float4*)&Bs[tx * 4 + p][k4 * 4];
#pragma unroll
      for (int q = 0; q < 4; ++q)
#pragma unroll
        for (int p = 0; p < 4; ++p) {
          acc[q][p] = fmaf(av[q].x, bv[p].x, acc[q][p]);
          acc[q][p] = fmaf(av[q].y, bv[p].y, acc[q][p]);
          acc[q][p] = fmaf(av[q].z, bv[p].z, acc[q][p]);
          acc[q][p] = fmaf(av[q].w, bv[p].w, acc[q][p]);
        }
    }
    __syncthreads();
  }
  int nbase = n0 + tx * 4;
  float bb4[4];
#pragma unroll
  for (int p = 0; p < 4; ++p) {
    int n = nbase + p;
    bb4[p] = (n < kG) ? bf[n] : bb[n - kG];
  }
#pragma unroll
  for (int q = 0; q < 4; ++q) {
    int m = m0 + ty * 4 + q;
    float4 o = make_float4(acc[q][0] + bb4[0], acc[q][1] + bb4[1],
                           acc[q][2] + bb4[2], acc[q][3] + bb4[3]);
    *((float4*)(Cc + (size_t)m * kGN + nbase)) = o;
  }
}

// GRU scan: one block per (b, dir). 768 thr: pair (j = tid>>1 of 384 outputs, s = half of K).
__global__ __launch_bounds__(768) void k_gru(const float* gi, const float* whh_f, const float* whh_b,
                                             const float* bhh_f, const float* bhh_b, float* H1) {
  int blk = blockIdx.x;
  int b = blk >> 1, dir = blk & 1;
  const float* whh = dir ? whh_b : whh_f;
  const float* bhh = dir ? bhh_b : bhh_f;
  int tid = threadIdx.x;
  int j = tid >> 1, s = tid & 1;
  float w[64];
  {
    const float4* wr = (const float4*)(whh + (size_t)j * kH + s * 64);
#pragma unroll
    for (int i = 0; i < 16; ++i) {
      float4 v = wr[i];
      w[4 * i] = v.x; w[4 * i + 1] = v.y; w[4 * i + 2] = v.z; w[4 * i + 3] = v.w;
    }
  }
  __shared__ alignas(16) float h_sh[kH];
  __shared__ float gh_sh[kG];
  if (tid < kH) h_sh[tid] = 0.f;
  float hreg = 0.f, hsum = 0.f;
  float bhr = 0.f, bhz = 0.f, bhn = 0.f;
  float gr = 0.f, gz = 0.f, gn = 0.f;
  const float* gp = nullptr;
  long rowstep = dir ? -(long)kGN : (long)kGN;
  if (tid < kH) {
    bhr = bhh[tid]; bhz = bhh[tid + kH]; bhn = bhh[tid + 2 * kH];
    gp = gi + ((size_t)b * kL + (dir ? (kL - 1) : 0)) * kGN + dir * kG + tid;
    gr = gp[0]; gz = gp[kH]; gn = gp[2 * kH];
  }
  __syncthreads();
  for (int t = 0; t < kL; ++t) {
    float nr = 0.f, nz = 0.f, nn2 = 0.f;
    if (tid < kH) {
      const float* gq = (t < kL - 1) ? (gp + rowstep) : gp;
      nr = gq[0]; nz = gq[kH]; nn2 = gq[2 * kH];
    }
    float a0 = 0.f, a1 = 0.f, a2 = 0.f, a3 = 0.f;
    const float4* hp = (const float4*)(h_sh + (s << 6));
#pragma unroll
    for (int i = 0; i < 16; ++i) {
      float4 hx = hp[i];
      a0 = fmaf(hx.x, w[4 * i], a0);
      a1 = fmaf(hx.y, w[4 * i + 1], a1);
      a2 = fmaf(hx.z, w[4 * i + 2], a2);
      a3 = fmaf(hx.w, w[4 * i + 3], a3);
    }
    float acc = (a0 + a1) + (a2 + a3);
    acc += __shfl_xor(acc, 1);
    if (s == 0) gh_sh[j] = acc;
    __syncthreads();
    if (tid < kH) {
      float hr = gh_sh[tid] + bhr;
      float hz = gh_sh[tid + kH] + bhz;
      float hn = gh_sh[tid + 2 * kH] + bhn;
      float r = sigm(gr + hr);
      float z = sigm(gz + hz);
      float n = tanh_fast(gn + r * hn);
      hreg = (1.f - z) * n + z * hreg;
      hsum += hreg;
      h_sh[tid] = hreg;
      gr = nr; gz = nz; gn = nn2;
      gp += rowstep;
    }
    __syncthreads();
  }
  if (tid < kH) H1[b * kD + dir * kH + tid] = hsum * (1.f / (float)kL);
}

// c[b][d] = sum_i vec[b][i]*W6bT[i][d] + W6_b[d]
__global__ void k_ctxproj(const float* vec, const float* W6bT, const float* w6bias, float* out) {
  __shared__ float vrow[kD];
  int b = blockIdx.x, d = threadIdx.x;
  vrow[d] = vec[b * kD + d];
  __syncthreads();
  float acc = w6bias[d];
  for (int i = 0; i < kD; ++i) acc = fmaf(vrow[i], W6bT[i * kD + d], acc);
  out[b * kD + d] = acc;
}

// U_F = tanh(F_hat@W6a.T + c1) ; scoresF = U_F@V1 ; block = (nchunk16, b)
__global__ void k_attn1(const float* Fhat, const float* W6aT, const float* c1,
                        const float* V1, float* UF, float* scF) {
  int b = blockIdx.y, n0 = blockIdx.x * 16, d = threadIdx.x;
  __shared__ float fr[16][kD];
  __shared__ float red[16][8];
  for (int r = 0; r < 16; ++r) fr[r][d] = Fhat[((size_t)b * kN + n0 + r) * kD + d];
  __syncthreads();
  float u[16];
#pragma unroll
  for (int n = 0; n < 16; ++n) u[n] = 0.f;
  for (int i = 0; i < kD; ++i) {
    float w = W6aT[i * kD + d];
#pragma unroll
    for (int n = 0; n < 16; ++n) u[n] = fmaf(fr[n][i], w, u[n]);
  }
  float cb = c1[b * kD + d];
  float v1 = V1[d];
  int lane = d & 63, wv = d >> 6;
#pragma unroll
  for (int n = 0; n < 16; ++n) {
    float uu = tanh_fast(u[n] + cb);
    UF[((size_t)b * kN + n0 + n) * kD + d] = uu;
    float p = uu * v1;
    p += __shfl_xor(p, 1); p += __shfl_xor(p, 2); p += __shfl_xor(p, 4);
    p += __shfl_xor(p, 8); p += __shfl_xor(p, 16); p += __shfl_xor(p, 32);
    if (lane == 0) red[n][wv] = p;
  }
  __syncthreads();
  if (d < 16) scF[b * kN + n0 + d] = red[d][0] + red[d][1] + red[d][2] + red[d][3];
}

// softmax over N + weighted sum -> Hf
__global__ void k_attn1_fin(const float* scF, const float* UF, float* Hf) {
  int b = blockIdx.x, d = threadIdx.x;
  __shared__ float al[kN];
  __shared__ float red[4];
  float sv = scF[b * kN + d];
  float m = sv;
#pragma unroll
  for (int o = 1; o < 64; o <<= 1) m = fmaxf(m, __shfl_xor(m, o));
  if ((d & 63) == 0) red[d >> 6] = m;
  __syncthreads();
  float mm = fmaxf(fmaxf(red[0], red[1]), fmaxf(red[2], red[3]));
  float e = __expf(sv - mm);
  float s = e;
#pragma unroll
  for (int o = 1; o < 64; o <<= 1) s += __shfl_xor(s, o);
  __syncthreads();
  if ((d & 63) == 0) red[d >> 6] = s;
  __syncthreads();
  float tot = red[0] + red[1] + red[2] + red[3];
  al[d] = e / tot;
  __syncthreads();
  float acc = 0.f;
  for (int n = 0; n < kN; ++n) acc = fmaf(al[n], UF[((size_t)b * kN + n) * kD + d], acc);
  Hf[b * kD + d] = acc;
}

// fold conv weights with W6a: effW[tapg][i][d] = sum_j conv_w[j,i,tap] * W6aT[j][d]
__global__ void k_fold(const float* cw1, const float* cw2, const float* cw3,
                       const float* W6aT, float* effW) {
  int tapg = blockIdx.y, i0 = blockIdx.x * 4, d = threadIdx.x;
  const float* cw; int K, tap;
  if (tapg < 3)      { cw = cw1; K = 3; tap = tapg; }
  else if (tapg < 7) { cw = cw2; K = 4; tap = tapg - 3; }
  else               { cw = cw3; K = 5; tap = tapg - 7; }
  __shared__ float cc[4][kD];
#pragma unroll
  for (int ii = 0; ii < 4; ++ii)
    cc[ii][d] = cw[((size_t)d * kD + (i0 + ii)) * K + tap];
  __syncthreads();
  float acc[4] = {0.f, 0.f, 0.f, 0.f};
  for (int jj = 0; jj < kD; ++jj) {
    float w = W6aT[jj * kD + d];
#pragma unroll
    for (int ii = 0; ii < 4; ++ii) acc[ii] = fmaf(cc[ii][jj], w, acc[ii]);
  }
#pragma unroll
  for (int ii = 0; ii < 4; ++ii)
    effW[((size_t)tapg * kD + i0 + ii) * kD + d] = acc[ii];
}

__global__ void k_effb(const float* b1, const float* b2, const float* b3,
                       const float* W6aT, float* effB) {
  int c = blockIdx.x, d = threadIdx.x;
  const float* bb = (c == 0) ? b1 : ((c == 1) ? b2 : b3);
  __shared__ float bl[kD];
  bl[d] = bb[d];
  __syncthreads();
  float acc = 0.f;
  for (int j = 0; j < kD; ++j) acc = fmaf(bl[j], W6aT[j * kD + d], acc);
  effB[c * kD + d] = acc;
}

// conv (folded) -> U = tanh(.) + scores = U@V2. block = (t-tile32, b); 256 thr = 64 d-groups x 4 t-groups.
template <int K>
__global__ __launch_bounds__(256) void k_conv(const float* xe, const float* effW, const float* effBc,
                                              const float* c2, const float* V2, float* U, float* scores,
                                              int tapbase, int Toff, int Tk) {
  int b = blockIdx.y;
  int t0 = blockIdx.x * 32;
  int tid = threadIdx.x;
  int tx = tid & 63, ty = tid >> 6;
  int d0 = tx * 4;
  __shared__ alignas(16) float xl[32 + K - 1][kD];
  {
    constexpr int nrow = 32 + K - 1;
    constexpr int total4 = nrow * 64;
    for (int g = tid; g < total4; g += 256) {
      int r = g >> 6, c4 = g & 63;
      int row = t0 + r; if (row > kL - 1) row = kL - 1;
      ((float4*)&xl[r][0])[c4] = ((const float4*)(xe + ((size_t)b * kL + row) * kD))[c4];
    }
  }
  __syncthreads();
  float acc[8][4];
#pragma unroll
  for (int tt = 0; tt < 8; ++tt)
#pragma unroll
    for (int q = 0; q < 4; ++q) acc[tt][q] = 0.f;
  for (int tap = 0; tap < K; ++tap) {
    const float* wq = effW + (size_t)(tapbase + tap) * kD * kD + d0;
    int rbase = ty * 8 + tap;
#pragma unroll 2
    for (int i = 0; i < kD; i += 4) {
      float4 xv[8];
#pragma unroll
      for (int tt = 0; tt < 8; ++tt) xv[tt] = *(const float4*)&xl[rbase + tt][i];
#pragma unroll
      for (int c = 0; c < 4; ++c) {
        float4 w4 = *(const float4*)(wq + (size_t)(i + c) * kD);
#pragma unroll
        for (int tt = 0; tt < 8; ++tt) {
          float xc = (c == 0) ? xv[tt].x : (c == 1) ? xv[tt].y : (c == 2) ? xv[tt].z : xv[tt].w;
          acc[tt][0] = fmaf(xc, w4.x, acc[tt][0]);
          acc[tt][1] = fmaf(xc, w4.y, acc[tt][1]);
          acc[tt][2] = fmaf(xc, w4.z, acc[tt][2]);
          acc[tt][3] = fmaf(xc, w4.w, acc[tt][3]);
        }
      }
    }
  }
  float4 eb = *(const float4*)(effBc + d0);
  float4 cc = *(const float4*)(c2 + (size_t)b * kD + d0);
  float4 v2 = *(const float4*)(V2 + d0);
#pragma unroll
  for (int tt = 0; tt < 8; ++tt) {
    int t = t0 + ty * 8 + tt;
    bool valid = (t < Tk);
    float u0 = tanh_fast(acc[tt][0] + eb.x + cc.x);
    float u1 = tanh_fast(acc[tt][1] + eb.y + cc.y);
    float u2 = tanh_fast(acc[tt][2] + eb.z + cc.z);
    float u3 = tanh_fast(acc[tt][3] + eb.w + cc.w);
    if (valid) {
      float4 o = make_float4(u0, u1, u2, u3);
      *((float4*)(U + ((size_t)b * kTT + Toff + t) * kD + d0)) = o;
    }
    float p = u0 * v2.x + u1 * v2.y + u2 * v2.z + u3 * v2.w;
    p += __shfl_xor(p, 1); p += __shfl_xor(p, 2); p += __shfl_xor(p, 4);
    p += __shfl_xor(p, 8); p += __shfl_xor(p, 16); p += __shfl_xor(p, 32);
    if (tx == 0 && valid) scores[(size_t)b * kTT + Toff + t] = p;
  }
}

// softmax over 6135 (in-place -> alpha)
__global__ void k_sm2(float* sc) {
  int b = blockIdx.x, tid = threadIdx.x;
  __shared__ float red[4];
  float m = -1e30f;
  for (int t = tid; t < kTT; t += 256) m = fmaxf(m, sc[(size_t)b * kTT + t]);
#pragma unroll
  for (int o = 1; o < 64; o <<= 1) m = fmaxf(m, __shfl_xor(m, o));
  if ((tid & 63) == 0) red[tid >> 6] = m;
  __syncthreads();
  float mm = fmaxf(fmaxf(red[0], red[1]), fmaxf(red[2], red[3]));
  float s = 0.f;
  for (int t = tid; t < kTT; t += 256) s += __expf(sc[(size_t)b * kTT + t] - mm);
#pragma unroll
  for (int o = 1; o < 64; o <<= 1) s += __shfl_xor(s, o);
  __syncthreads();
  if ((tid & 63) == 0) red[tid >> 6] = s;
  __syncthreads();
  float inv = 1.f / (red[0] + red[1] + red[2] + red[3]);
  for (int t = tid; t < kTT; t += 256) sc[(size_t)b * kTT + t] = __expf(sc[(size_t)b * kTT + t] - mm) * inv;
}

// weighted-sum partials over t-chunks of 128
__global__ void k_aws(const float* sc, const float* U, float* part) {
  int cchunk = blockIdx.x, b = blockIdx.y, d = threadIdx.x;
  int tbeg = cchunk * 128;
  int tend = tbeg + 128; if (tend > kTT) tend = kTT;
  float acc = 0.f;
  for (int t = tbeg; t < tend; ++t)
    acc = fmaf(sc[(size_t)b * kTT + t], U[((size_t)b * kTT + t) * kD + d], acc);
  part[((size_t)cchunk * kB + b) * kD + d] = acc;
}

__global__ void k_ared(const float* part, float* Ht) {
  int b = blockIdx.x, d = threadIdx.x;
  float acc = 0.f;
  for (int cc = 0; cc < 48; ++cc) acc += part[((size_t)cc * kB + b) * kD + d];
  Ht[b * kD + d] = acc;
}

// classifier: relu([Hf,Ht]@cls1.T + b1)@cls2.T + b2
__global__ __launch_bounds__(1024) void k_cls(const float* Hf, const float* Ht,
                                              const float* w1, const float* b1,
                                              const float* w2, const float* b2, float* out) {
  int b = blockIdx.x, tid = threadIdx.x;
  __shared__ alignas(16) float hc[2 * kD];
  __shared__ alignas(16) float act[1024];
  if (tid < kD) hc[tid] = Hf[b * kD + tid];
  else if (tid < 2 * kD) hc[tid] = Ht[b * kD + tid - kD];
  __syncthreads();
  {
    float acc = b1[tid];
    const float4* wr = (const float4*)(w1 + (size_t)tid * 2 * kD);
    const float4* hr = (const float4*)hc;
    for (int i = 0; i < 128; ++i) {
      float4 wv = wr[i]; float4 hv = hr[i];
      acc += wv.x * hv.x + wv.y * hv.y + wv.z * hv.z + wv.w * hv.w;
    }
    act[tid] = acc > 0.f ? acc : 0.f;
  }
  __syncthreads();
  if (tid < kC) {
    float acc = b2[tid];
    const float4* wr = (const float4*)(w2 + (size_t)tid * 1024);
    const float4* ar = (const float4*)act;
    for (int i = 0; i < 256; ++i) {
      float4 wv = wr[i]; float4 av = ar[i];
      acc += wv.x * av.x + wv.y * av.y + wv.z * av.z + wv.w * av.w;
    }
    out[b * kC + tid] = acc;
  }
}

extern "C" void kernel_launch(void* const* d_in, const int* in_sizes, int n_in,
                              void* d_out, int out_size, void* d_ws, size_t ws_size,
                              hipStream_t stream) {
  (void)in_sizes; (void)n_in; (void)out_size; (void)ws_size;
  const int*   x     = (const int*)d_in[0];
  const int*   nodes = (const int*)d_in[2];
  const float* nmask = (const float*)d_in[3];
  const float* DDm   = (const float*)d_in[4];
  const float* DF    = (const float*)d_in[5];
  const float* wemb  = (const float*)d_in[6];
  const float* lemb  = (const float*)d_in[7];
  const float* eemb  = (const float*)d_in[8];
  const float* W1    = (const float*)d_in[9];
  const float* W2    = (const float*)d_in[10];
  const float* W3    = (const float*)d_in[11];
  const float* W4    = (const float*)d_in[12];
  const float* W6w   = (const float*)d_in[13];
  const float* W6bia = (const float*)d_in[14];
  const float* V1v   = (const float*)d_in[15];
  const float* V2v   = (const float*)d_in[16];
  const float* wih_f = (const float*)d_in[17];
  const float* whh_f = (const float*)d_in[18];
  const float* bih_f = (const float*)d_in[19];
  const float* bhh_f = (const float*)d_in[20];
  const float* wih_b = (const float*)d_in[21];
  const float* whh_b = (const float*)d_in[22];
  const float* bih_b = (const float*)d_in[23];
  const float* bhh_b = (const float*)d_in[24];
  const float* c1w   = (const float*)d_in[25];
  const float* c1b   = (const float*)d_in[26];
  const float* c2w   = (const float*)d_in[27];
  const float* c2b   = (const float*)d_in[28];
  const float* c3w   = (const float*)d_in[29];
  const float* c3b   = (const float*)d_in[30];
  const float* cls1w = (const float*)d_in[31];
  const float* cls1b = (const float*)d_in[32];
  const float* cls2w = (const float*)d_in[33];
  const float* cls2b = (const float*)d_in[34];
  float* out = (float*)d_out;
  float* ws  = (float*)d_ws;

  float* xe   = ws + OFF_XE;
  float* gi   = ws + OFF_GI;
  float* Ubuf = ws + OFF_GI;   // overlay: U reuses gi space after the scan
  float* Fhat = ws + OFF_FHAT;
  float* UF   = ws + OFF_UF;
  float* effW = ws + OFF_EFFW;
  float* effB = ws + OFF_EFFB;
  float* w6at = ws + OFF_W6AT;
  float* w6bt = ws + OFF_W6BT;
  float* w1t  = ws + OFF_W1T;
  float* w2t  = ws + OFF_W2T;
  float* w3t  = ws + OFF_W3T;
  float* w4t  = ws + OFF_W4T;
  float* dhat = ws + OFF_DHAT;
  float* p1   = ws + OFF_P1;
  float* p2   = ws + OFF_P2;
  float* p3   = ws + OFF_P3;
  float* rs   = ws + OFF_RS;
  float* cs   = ws + OFF_CS;
  float* H1b  = ws + OFF_H1;
  float* c1bf = ws + OFF_C1;
  float* Hfb  = ws + OFF_HFv;
  float* c2bf = ws + OFF_C2;
  float* Htb  = ws + OFF_HT;
  float* scF  = ws + OFF_SCF;
  float* sc   = ws + OFF_SC;
  float* part = ws + OFF_PART;

  // weight transposes
  k_transpose<<<kD, kD, 0, stream>>>(w1t, W1, kD);
  k_transpose<<<kD, kD, 0, stream>>>(w2t, W2, kD);
  k_transpose<<<kD, kD, 0, stream>>>(w3t, W3, kD);
  k_transpose<<<kD, kD, 0, stream>>>(w4t, W4, kD);
  k_transpose<<<kD, kD, 0, stream>>>(w6at, W6w, 2 * kD);
  k_transpose<<<kD, kD, 0, stream>>>(w6bt, W6w + kD, 2 * kD);

  // graph branch
  k_rowcol<<<1, kA, 0, stream>>>(DDm, rs, cs);
  k_proj3<<<kA, kD, 0, stream>>>(lemb, w1t, w2t, w3t, p1, p2, p3);
  k_dhat<<<kA, kD, 0, stream>>>(DDm, p1, p2, p3, rs, cs, dhat);
  k_fhat<<<dim3(16, kB), kD, 0, stream>>>(nodes, nmask, eemb, DF, w4t, dhat, Fhat);

  // embeddings + GRU input projection + scan
  k_xe<<<2048, 256, 0, stream>>>(x, wemb, xe);
  k_gemm_gi<<<dim3(512, 12), 256, 0, stream>>>(xe, wih_f, wih_b, bih_f, bih_b, gi);
  k_gru<<<32, 768, 0, stream>>>(gi, whh_f, whh_b, bhh_f, bhh_b, H1b);

  // attn pool 1 over F_hat
  k_ctxproj<<<kB, kD, 0, stream>>>(H1b, w6bt, W6bia, c1bf);
  k_attn1<<<dim3(16, kB), kD, 0, stream>>>(Fhat, w6at, c1bf, V1v, UF, scF);
  k_attn1_fin<<<kB, kD, 0, stream>>>(scF, UF, Hfb);
  k_ctxproj<<<kB, kD, 0, stream>>>(Hfb, w6bt, W6bia, c2bf);

  // folded convs -> U (+ scores), overlaying gi
  k_fold<<<dim3(64, 12), kD, 0, stream>>>(c1w, c2w, c3w, w6at, effW);
  k_effb<<<3, kD, 0, stream>>>(c1b, c2b, c3b, w6at, effB);
  k_conv<3><<<dim3(64, kB), 256, 0, stream>>>(xe, effW, effB + 0,      c2bf, V2v, Ubuf, sc, 0, 0,         kT1);
  k_conv<4><<<dim3(64, kB), 256, 0, stream>>>(xe, effW, effB + kD,     c2bf, V2v, Ubuf, sc, 3, kT1,       kT2);
  k_conv<5><<<dim3(64, kB), 256, 0, stream>>>(xe, effW, effB + 2 * kD, c2bf, V2v, Ubuf, sc, 7, kT1 + kT2, kT3);

  // attn pool 2 + classifier
  k_sm2<<<kB, 256, 0, stream>>>(sc);
  k_aws<<<dim3(48, kB), kD, 0, stream>>>(sc, Ubuf, part);
  k_ared<<<kB, kD, 0, stream>>>(part, Htb);
  k_cls<<<kB, 1024, 0, stream>>>(Hfb, Htb, cls1w, cls1b, cls2w, cls2b, out);
}

// Round 2
// 2197.100 us; speedup vs baseline: 1.5960x; 1.5960x over previous
//
#include <hip/hip_runtime.h>
#include <cstdint>
#include <cstddef>

// ---------------- constants ----------------
constexpr int kB = 16, kL = 2048, kD = 256, kA = 128, kN = 256, kC = 128;
constexpr int kH = 128, kG = 384, kGN = 768;               // GRU: 3H=384, both dirs = 768
constexpr int kT1 = 2046, kT2 = 2045, kT3 = 2044, kTT = 6135;
constexpr float kEPS = 1e-5f;

// conv tiling in fused kernel
constexpr int kCTile = 48;                 // t-positions per conv block
constexpr int kCBlkPerSeg = 43 * kB;       // ceil(2046/48)=43 tiles x 16 batches = 688
constexpr int kConvBlocks = 3 * kCBlkPerSeg;  // 2064
constexpr int kGruBlocks = 32;

// ---------------- workspace layout (floats) ----------------
constexpr size_t OFF_XE   = 0;                                   // [B*L, 256]
constexpr size_t OFF_GI   = OFF_XE + (size_t)kB*kL*kD;           // [B*L, 768]
constexpr size_t OFF_FHAT = OFF_GI + (size_t)kB*kL*kGN;          // [B,N,D]
constexpr size_t OFF_UF   = OFF_FHAT + (size_t)kB*kN*kD;         // [B,N,D]
constexpr size_t OFF_EFFW = OFF_UF + (size_t)kB*kN*kD;           // [12,256,256]
constexpr size_t OFF_EFFB = OFF_EFFW + (size_t)12*kD*kD;         // [3,256]
constexpr size_t OFF_W6AT = OFF_EFFB + (size_t)3*kD;             // [256,256]
constexpr size_t OFF_W6BT = OFF_W6AT + (size_t)kD*kD;
constexpr size_t OFF_W1T  = OFF_W6BT + (size_t)kD*kD;
constexpr size_t OFF_W2T  = OFF_W1T + (size_t)kD*kD;
constexpr size_t OFF_W3T  = OFF_W2T + (size_t)kD*kD;
constexpr size_t OFF_W4T  = OFF_W3T + (size_t)kD*kD;
constexpr size_t OFF_DHAT = OFF_W4T + (size_t)kD*kD;             // [A,D]
constexpr size_t OFF_P1   = OFF_DHAT + (size_t)kA*kD;
constexpr size_t OFF_P2   = OFF_P1 + (size_t)kA*kD;
constexpr size_t OFF_P3   = OFF_P2 + (size_t)kA*kD;
constexpr size_t OFF_RS   = OFF_P3 + (size_t)kA*kD;              // [A]
constexpr size_t OFF_CS   = OFF_RS + kA;                         // [A]
constexpr size_t OFF_H1   = OFF_CS + kA;                         // [B,256]
constexpr size_t OFF_C1   = OFF_H1 + (size_t)kB*kD;
constexpr size_t OFF_HFv  = OFF_C1 + (size_t)kB*kD;
constexpr size_t OFF_C2   = OFF_HFv + (size_t)kB*kD;
constexpr size_t OFF_HT   = OFF_C2 + (size_t)kB*kD;
constexpr size_t OFF_SCF  = OFF_HT + (size_t)kB*kD;              // [B,N]
constexpr size_t OFF_SC   = OFF_SCF + (size_t)kB*kN;             // [B,6135]
constexpr size_t OFF_PART = OFF_SC + (size_t)kB*kTT;             // [48,B,256]
constexpr size_t OFF_PBUF = OFF_PART + (size_t)48*kB*kD;         // [B,6135,256] (concurrent path)
constexpr size_t TOTAL_CONCURRENT = OFF_PBUF + (size_t)kB*kTT*kD;

// ---------------- small helpers ----------------
__device__ __forceinline__ float sigm(float x) { return 1.f / (1.f + __expf(-x)); }
__device__ __forceinline__ float tanh_fast(float x) {
  x = fminf(15.f, fmaxf(-15.f, x));
  float e2 = __expf(2.f * x);
  return (e2 - 1.f) / (e2 + 1.f);
}

// dst[i*256 + d] = src[d*stride + i]   (256x256 transpose)
__global__ void k_transpose(float* dst, const float* src, int stride) {
  int i = blockIdx.x, d = threadIdx.x;
  dst[i * kD + d] = src[(size_t)d * stride + i];
}

__global__ void k_rowcol(const float* DDm, float* rs, float* cs) {
  int a = threadIdx.x; // 128
  float r = 0.f, c = 0.f;
  for (int j = 0; j < kA; ++j) { r += DDm[a * kA + j]; c += DDm[j * kA + a]; }
  rs[a] = r; cs[a] = c;
}

__global__ void k_proj3(const float* Dm, const float* W1T, const float* W2T, const float* W3T,
                        float* P1, float* P2, float* P3) {
  __shared__ float row[kD];
  int a = blockIdx.x, d = threadIdx.x;
  row[d] = Dm[a * kD + d];
  __syncthreads();
  float s1 = 0, s2 = 0, s3 = 0;
  for (int i = 0; i < kD; ++i) {
    float v = row[i];
    s1 = fmaf(v, W1T[i * kD + d], s1);
    s2 = fmaf(v, W2T[i * kD + d], s2);
    s3 = fmaf(v, W3T[i * kD + d], s3);
  }
  P1[a * kD + d] = s1; P2[a * kD + d] = s2; P3[a * kD + d] = s3;
}

__global__ void k_dhat(const float* DDm, const float* P1, const float* P2, const float* P3,
                       const float* rs, const float* cs, float* Dhat) {
  __shared__ float drow[kA], dcol[kA];
  int a = blockIdx.x, d = threadIdx.x;
  if (d < kA) { drow[d] = DDm[a * kA + d]; dcol[d] = DDm[d * kA + a]; }
  __syncthreads();
  float q2 = 0, q3 = 0;
  for (int j = 0; j < kA; ++j) {
    q2 = fmaf(drow[j], P2[j * kD + d], q2);
    q3 = fmaf(dcol[j], P3[j * kD + d], q3);
  }
  float v = P1[a * kD + d] + q2 / (rs[a] + kEPS) + q3 / (cs[a] + kEPS);
  Dhat[a * kD + d] = v > 0.f ? v : 0.f;
}

__global__ void k_fhat(const int* nodes, const float* nmask, const float* eemb,
                       const float* DF, const float* W4T, const float* Dhat, float* Fhat) {
  int b = blockIdx.y, n0 = blockIdx.x * 16, d = threadIdx.x;
  __shared__ float fm[16][kD];
  __shared__ float dc[kA][16];
  __shared__ float den[16], msk[16];
  for (int r = 0; r < 16; ++r) {
    int idx = nodes[b * kN + n0 + r];
    float m = nmask[b * kN + n0 + r];
    fm[r][d] = eemb[(size_t)idx * kD + d] * m;
    if (d == 0) msk[r] = m;
  }
  for (int q = 0; q < 8; ++q) {
    int e = q * 256 + d;
    int aa = e >> 4, nn = e & 15;
    dc[aa][nn] = DF[(size_t)b * kA * kN + (size_t)aa * kN + n0 + nn];
  }
  __syncthreads();
  if (d < 16) {
    float s = 0.f;
    for (int aa = 0; aa < kA; ++aa) s += dc[aa][d];
    den[d] = s;
  }
  __syncthreads();
  float a1[16], a2[16];
#pragma unroll
  for (int n = 0; n < 16; ++n) { a1[n] = 0.f; a2[n] = 0.f; }
  for (int i = 0; i < kD; ++i) {
    float w = W4T[i * kD + d];
#pragma unroll
    for (int n = 0; n < 16; ++n) a1[n] = fmaf(fm[n][i], w, a1[n]);
  }
  for (int aa = 0; aa < kA; ++aa) {
    float w = Dhat[aa * kD + d];
#pragma unroll
    for (int n = 0; n < 16; ++n) a2[n] = fmaf(dc[aa][n], w, a2[n]);
  }
#pragma unroll
  for (int n = 0; n < 16; ++n) {
    float v = a1[n] + a2[n] / (den[n] + kEPS);
    v = v > 0.f ? v : 0.f;
    Fhat[((size_t)b * kN + n0 + n) * kD + d] = v * msk[n];
  }
}

__global__ void k_xe(const int* x, const float* wemb, float* xe) {
  int r0 = blockIdx.x * 16;
  int t = threadIdx.x;
  int rr = t >> 6, c = t & 63;
  for (int s = 0; s < 4; ++s) {
    int r = r0 + rr + s * 4;
    int idx = x[r];
    ((float4*)(xe + (size_t)r * kD))[c] = ((const float4*)(wemb + (size_t)idx * kD))[c];
  }
}

// gi[32768 x 768] = xe[32768x256] @ [wih_f;wih_b]^T + bias
__global__ __launch_bounds__(256) void k_gemm_gi(const float* Aa, const float* wf, const float* wb,
                                                 const float* bf, const float* bb, float* Cc) {
  __shared__ alignas(16) float As[64][68];
  __shared__ alignas(16) float Bs[64][68];
  int m0 = blockIdx.x * 64, n0 = blockIdx.y * 64;
  int tid = threadIdx.x;
  int tx = tid & 15, ty = tid >> 4;
  float acc[4][4];
#pragma unroll
  for (int q = 0; q < 4; ++q)
#pragma unroll
    for (int p = 0; p < 4; ++p) acc[q][p] = 0.f;
  for (int kk = 0; kk < 256; kk += 64) {
    {
      int r = tid >> 2, c0 = (tid & 3) * 16;
      const float* src = Aa + (size_t)(m0 + r) * kD + kk + c0;
      float4 v0 = ((const float4*)src)[0], v1 = ((const float4*)src)[1];
      float4 v2 = ((const float4*)src)[2], v3 = ((const float4*)src)[3];
      *((float4*)&As[r][c0])      = v0; *((float4*)&As[r][c0 + 4])  = v1;
      *((float4*)&As[r][c0 + 8])  = v2; *((float4*)&As[r][c0 + 12]) = v3;
      int n = n0 + r;
      const float* wsrc = (n < kG) ? (wf + (size_t)n * kD) : (wb + (size_t)(n - kG) * kD);
      wsrc += kk + c0;
      float4 w0 = ((const float4*)wsrc)[0], w1 = ((const float4*)wsrc)[1];
      float4 w2 = ((const float4*)wsrc)[2], w3 = ((const float4*)wsrc)[3];
      *((float4*)&Bs[r][c0])      = w0; *((float4*)&Bs[r][c0 + 4])  = w1;
      *((float4*)&Bs[r][c0 + 8])  = w2; *((float4*)&Bs[r][c0 + 12]) = w3;
    }
    __syncthreads();
#pragma unroll 4
    for (int k4 = 0; k4 < 16; ++k4) {
      float4 av[4], bv[4];
#pragma unroll
      for (int q = 0; q < 4; ++q) av[q] = *(const float4*)&As[ty * 4 + q][k4 * 4];
#pragma unroll
      for (int p = 0; p < 4; ++p) bv[p] = *(const float4*)&Bs[tx * 4 + p][k4 * 4];
#pragma unroll
      for (int q = 0; q < 4; ++q)
#pragma unroll
        for (int p = 0; p < 4; ++p) {
          acc[q][p] = fmaf(av[q].x, bv[p].x, acc[q][p]);
          acc[q][p] = fmaf(av[q].y, bv[p].y, acc[q][p]);
          acc[q][p] = fmaf(av[q].z, bv[p].z, acc[q][p]);
          acc[q][p] = fmaf(av[q].w, bv[p].w, acc[q][p]);
        }
    }
    __syncthreads();
  }
  int nbase = n0 + tx * 4;
  float bb4[4];
#pragma unroll
  for (int p = 0; p < 4; ++p) {
    int n = nbase + p;
    bb4[p] = (n < kG) ? bf[n] : bb[n - kG];
  }
#pragma unroll
  for (int q = 0; q < 4; ++q) {
    int m = m0 + ty * 4 + q;
    float4 o = make_float4(acc[q][0] + bb4[0], acc[q][1] + bb4[1],
                           acc[q][2] + bb4[2], acc[q][3] + bb4[3]);
    *((float4*)(Cc + (size_t)m * kGN + nbase)) = o;
  }
}

// ---------------- FUSED kernel: GRU scan (blocks 0..31) + conv pre-activation (blocks 32+) ----
// h layout in LDS: chunk c (32 floats) at float offset c*36 -> conflict-free b128 reads.
__device__ __forceinline__ int hpad(int i) { return (i >> 5) * 36 + (i & 31); }

__global__ __launch_bounds__(768, 3) void k_main(
    const float* __restrict__ gi, const float* __restrict__ whh_f, const float* __restrict__ whh_b,
    const float* __restrict__ bhh_f, const float* __restrict__ bhh_b, float* __restrict__ H1,
    const float* __restrict__ xe, const float* __restrict__ effW, const float* __restrict__ effB,
    float* __restrict__ P, int idOffset) {
  __shared__ alignas(16) float smem[(kCTile + 4) * kD];   // 52*256 floats = 53 KB
  int id = blockIdx.x + idOffset;
  int tid = threadIdx.x;

  if (id < kGruBlocks) {
    // ---------------- GRU path ----------------
    int b = id >> 1, dir = id & 1;
    const float* whh = dir ? whh_b : whh_f;
    const float* bhh = dir ? bhh_b : bhh_f;
    float* h_sh = smem;          // floats [0,140)
    float* gh   = smem + 144;    // floats [144,528)

    int s = tid & 3;        // K-chunk of 32
    int g = tid >> 2;       // output pair index, 0..191
    // weights: w[q][k] = whh[(g*2+q)*128 + s*32 + k]
    float w[2][32];
#pragma unroll
    for (int q = 0; q < 2; ++q) {
      const float4* wp = (const float4*)(whh + (size_t)(g * 2 + q) * kH + s * 32);
#pragma unroll
      for (int r = 0; r < 8; ++r) {
        float4 v = wp[r];
        w[q][4 * r] = v.x; w[q][4 * r + 1] = v.y; w[q][4 * r + 2] = v.z; w[q][4 * r + 3] = v.w;
      }
    }
    for (int i = tid; i < 144; i += 768) h_sh[i] = 0.f;

    float hreg = 0.f, hsum = 0.f;
    float bhr = 0.f, bhz = 0.f, bhn = 0.f;
    float ar = 0.f, az = 0.f, an = 0.f;   // buf A (even t)
    float br = 0.f, bz = 0.f, bn = 0.f;   // buf B (odd t)
    const float* gib = gi + (size_t)b * kL * kGN + dir * kG + tid;
    if (tid < kH) {
      bhr = bhh[tid]; bhz = bhh[tid + kH]; bhn = bhh[tid + 2 * kH];
      const float* r0 = gib + (size_t)(dir ? (kL - 1) : 0) * kGN;
      const float* r1 = gib + (size_t)(dir ? (kL - 2) : 1) * kGN;
      ar = r0[0]; az = r0[kH]; an = r0[2 * kH];
      br = r1[0]; bz = r1[kH]; bn = r1[2 * kH];
    }
    __syncthreads();

#define GRU_STEP(cr, cz, cn, T)                                                   \
    {                                                                             \
      const float* hp = h_sh + s * 36;                                            \
      float4 h0 = *(const float4*)(hp + 0),  h1 = *(const float4*)(hp + 4);       \
      float4 h2 = *(const float4*)(hp + 8),  h3 = *(const float4*)(hp + 12);      \
      float4 h4 = *(const float4*)(hp + 16), h5 = *(const float4*)(hp + 20);      \
      float4 h6 = *(const float4*)(hp + 24), h7 = *(const float4*)(hp + 28);      \
      float a0 = 0.f, a1 = 0.f;                                                   \
      const float4 hv[8] = {h0, h1, h2, h3, h4, h5, h6, h7};                      \
      _Pragma("unroll")                                                           \
      for (int r = 0; r < 8; ++r) {                                               \
        float4 hh = hv[r];                                                        \
        a0 = fmaf(hh.x, w[0][4 * r], a0);     a1 = fmaf(hh.x, w[1][4 * r], a1);   \
        a0 = fmaf(hh.y, w[0][4 * r + 1], a0); a1 = fmaf(hh.y, w[1][4 * r + 1], a1);\
        a0 = fmaf(hh.z, w[0][4 * r + 2], a0); a1 = fmaf(hh.z, w[1][4 * r + 2], a1);\
        a0 = fmaf(hh.w, w[0][4 * r + 3], a0); a1 = fmaf(hh.w, w[1][4 * r + 3], a1);\
      }                                                                           \
      a0 += __shfl_xor(a0, 1); a0 += __shfl_xor(a0, 2);                           \
      a1 += __shfl_xor(a1, 1); a1 += __shfl_xor(a1, 2);                           \
      if (s == 0) { float2 o = make_float2(a0, a1); *(float2*)(gh + g * 2) = o; } \
      __syncthreads();                                                            \
      if (tid < kH) {                                                             \
        int tn = (T) + 2; if (tn > kL - 1) tn = kL - 1;                           \
        const float* gq = gib + (size_t)(dir ? (kL - 1 - tn) : tn) * kGN;         \
        float lr = gq[0], lz = gq[kH], ln = gq[2 * kH];                           \
        float hr = gh[tid] + bhr;                                                 \
        float hz = gh[tid + kH] + bhz;                                            \
        float hn = gh[tid + 2 * kH] + bhn;                                        \
        float rg = sigm(cr + hr);                                                 \
        float zg = sigm(cz + hz);                                                 \
        float ng = tanh_fast(cn + rg * hn);                                       \
        hreg = (1.f - zg) * ng + zg * hreg;                                       \
        hsum += hreg;                                                             \
        h_sh[hpad(tid)] = hreg;                                                   \
        cr = lr; cz = lz; cn = ln;                                                \
      }                                                                           \
      __syncthreads();                                                            \
    }

    for (int t = 0; t < kL; t += 2) {
      GRU_STEP(ar, az, an, t)
      GRU_STEP(br, bz, bn, t + 1)
    }
#undef GRU_STEP
    if (tid < kH) H1[b * kD + dir * kH + tid] = hsum * (1.f / (float)kL);

  } else {
    // ---------------- conv path: P[b, Toff+t, d] = sum_taps xe * effW + effB ----------------
    int cid = id - kGruBlocks;
    int seg = cid / kCBlkPerSeg;
    int rem = cid - seg * kCBlkPerSeg;
    int b = rem / 43;
    int tb = rem - b * 43;
    int t0 = tb * kCTile;
    int K = 3 + seg;
    int tapbase = (seg == 0) ? 0 : (seg == 1) ? 3 : 7;
    int Toff = (seg == 0) ? 0 : (seg == 1) ? kT1 : (kT1 + kT2);
    int Tk = (seg == 0) ? kT1 : (seg == 1) ? kT2 : kT3;

    float (*xl)[kD] = (float(*)[kD])smem;
    int nrow = kCTile + K - 1;  // <= 52
    {
      int total4 = nrow * 64;
      for (int gq = tid; gq < total4; gq += 768) {
        int r = gq >> 6, c4 = gq & 63;
        int row = t0 + r; if (row > kL - 1) row = kL - 1;
        ((float4*)&xl[r][0])[c4] = ((const float4*)(xe + ((size_t)b * kL + row) * kD))[c4];
      }
    }
    __syncthreads();

    int tx = tid & 63, tg = tid >> 6;   // 64 d-groups x 12 t-groups
    int d0 = tx * 4;
    float acc[4][4];
#pragma unroll
    for (int tt = 0; tt < 4; ++tt)
#pragma unroll
      for (int q = 0; q < 4; ++q) acc[tt][q] = 0.f;
    for (int tap = 0; tap < K; ++tap) {
      const float* wq = effW + (size_t)(tapbase + tap) * kD * kD + d0;
      int rbase = tg * 4 + tap;
#pragma unroll 2
      for (int i = 0; i < kD; i += 4) {
        float4 xv[4];
#pragma unroll
        for (int tt = 0; tt < 4; ++tt) xv[tt] = *(const float4*)&xl[rbase + tt][i];
#pragma unroll
        for (int c = 0; c < 4; ++c) {
          float4 w4 = *(const float4*)(wq + (size_t)(i + c) * kD);
#pragma unroll
          for (int tt = 0; tt < 4; ++tt) {
            float xc = (c == 0) ? xv[tt].x : (c == 1) ? xv[tt].y : (c == 2) ? xv[tt].z : xv[tt].w;
            acc[tt][0] = fmaf(xc, w4.x, acc[tt][0]);
            acc[tt][1] = fmaf(xc, w4.y, acc[tt][1]);
            acc[tt][2] = fmaf(xc, w4.z, acc[tt][2]);
            acc[tt][3] = fmaf(xc, w4.w, acc[tt][3]);
          }
        }
      }
    }
    float4 eb = *(const float4*)(effB + seg * kD + d0);
#pragma unroll
    for (int tt = 0; tt < 4; ++tt) {
      int t = t0 + tg * 4 + tt;
      if (t < Tk) {
        float4 o = make_float4(acc[tt][0] + eb.x, acc[tt][1] + eb.y,
                               acc[tt][2] + eb.z, acc[tt][3] + eb.w);
        *((float4*)(P + ((size_t)b * kTT + Toff + t) * kD + d0)) = o;
      }
    }
  }
}

// c[b][d] = sum_i vec[b][i]*W6bT[i][d] + W6_b[d]
__global__ void k_ctxproj(const float* vec, const float* W6bT, const float* w6bias, float* out) {
  __shared__ float vrow[kD];
  int b = blockIdx.x, d = threadIdx.x;
  vrow[d] = vec[b * kD + d];
  __syncthreads();
  float acc = w6bias[d];
  for (int i = 0; i < kD; ++i) acc = fmaf(vrow[i], W6bT[i * kD + d], acc);
  out[b * kD + d] = acc;
}

__global__ void k_attn1(const float* Fhat, const float* W6aT, const float* c1,
                        const float* V1, float* UF, float* scF) {
  int b = blockIdx.y, n0 = blockIdx.x * 16, d = threadIdx.x;
  __shared__ float fr[16][kD];
  __shared__ float red[16][8];
  for (int r = 0; r < 16; ++r) fr[r][d] = Fhat[((size_t)b * kN + n0 + r) * kD + d];
  __syncthreads();
  float u[16];
#pragma unroll
  for (int n = 0; n < 16; ++n) u[n] = 0.f;
  for (int i = 0; i < kD; ++i) {
    float w = W6aT[i * kD + d];
#pragma unroll
    for (int n = 0; n < 16; ++n) u[n] = fmaf(fr[n][i], w, u[n]);
  }
  float cb = c1[b * kD + d];
  float v1 = V1[d];
  int lane = d & 63, wv = d >> 6;
#pragma unroll
  for (int n = 0; n < 16; ++n) {
    float uu = tanh_fast(u[n] + cb);
    UF[((size_t)b * kN + n0 + n) * kD + d] = uu;
    float p = uu * v1;
    p += __shfl_xor(p, 1); p += __shfl_xor(p, 2); p += __shfl_xor(p, 4);
    p += __shfl_xor(p, 8); p += __shfl_xor(p, 16); p += __shfl_xor(p, 32);
    if (lane == 0) red[n][wv] = p;
  }
  __syncthreads();
  if (d < 16) scF[b * kN + n0 + d] = red[d][0] + red[d][1] + red[d][2] + red[d][3];
}

__global__ void k_attn1_fin(const float* scF, const float* UF, float* Hf) {
  int b = blockIdx.x, d = threadIdx.x;
  __shared__ float al[kN];
  __shared__ float red[4];
  float sv = scF[b * kN + d];
  float m = sv;
#pragma unroll
  for (int o = 1; o < 64; o <<= 1) m = fmaxf(m, __shfl_xor(m, o));
  if ((d & 63) == 0) red[d >> 6] = m;
  __syncthreads();
  float mm = fmaxf(fmaxf(red[0], red[1]), fmaxf(red[2], red[3]));
  float e = __expf(sv - mm);
  float s = e;
#pragma unroll
  for (int o = 1; o < 64; o <<= 1) s += __shfl_xor(s, o);
  __syncthreads();
  if ((d & 63) == 0) red[d >> 6] = s;
  __syncthreads();
  float tot = red[0] + red[1] + red[2] + red[3];
  al[d] = e / tot;
  __syncthreads();
  float acc = 0.f;
  for (int n = 0; n < kN; ++n) acc = fmaf(al[n], UF[((size_t)b * kN + n) * kD + d], acc);
  Hf[b * kD + d] = acc;
}

__global__ void k_fold(const float* cw1, const float* cw2, const float* cw3,
                       const float* W6aT, float* effW) {
  int tapg = blockIdx.y, i0 = blockIdx.x * 4, d = threadIdx.x;
  const float* cw; int K, tap;
  if (tapg < 3)      { cw = cw1; K = 3; tap = tapg; }
  else if (tapg < 7) { cw = cw2; K = 4; tap = tapg - 3; }
  else               { cw = cw3; K = 5; tap = tapg - 7; }
  __shared__ float cc[4][kD];
#pragma unroll
  for (int ii = 0; ii < 4; ++ii)
    cc[ii][d] = cw[((size_t)d * kD + (i0 + ii)) * K + tap];
  __syncthreads();
  float acc[4] = {0.f, 0.f, 0.f, 0.f};
  for (int jj = 0; jj < kD; ++jj) {
    float w = W6aT[jj * kD + d];
#pragma unroll
    for (int ii = 0; ii < 4; ++ii) acc[ii] = fmaf(cc[ii][jj], w, acc[ii]);
  }
#pragma unroll
  for (int ii = 0; ii < 4; ++ii)
    effW[((size_t)tapg * kD + i0 + ii) * kD + d] = acc[ii];
}

__global__ void k_effb(const float* b1, const float* b2, const float* b3,
                       const float* W6aT, float* effB) {
  int c = blockIdx.x, d = threadIdx.x;
  const float* bb = (c == 0) ? b1 : ((c == 1) ? b2 : b3);
  __shared__ float bl[kD];
  bl[d] = bb[d];
  __syncthreads();
  float acc = 0.f;
  for (int j = 0; j < kD; ++j) acc = fmaf(bl[j], W6aT[j * kD + d], acc);
  effB[c * kD + d] = acc;
}

// scores[b,t] = sum_d tanh(P[b,t,d] + c2[b,d]) * V2[d]
__global__ void k_score(const float* P, const float* c2, const float* V2, float* sc) {
  int b = blockIdx.y;
  int t0 = blockIdx.x * 32;
  int tid = threadIdx.x;
  int w = tid >> 6, lane = tid & 63;
  float4 c2v = ((const float4*)(c2 + (size_t)b * kD))[lane];
  float4 v2v = ((const float4*)V2)[lane];
#pragma unroll
  for (int it = 0; it < 8; ++it) {
    int t = t0 + it * 4 + w;
    if (t < kTT) {
      float4 p = ((const float4*)(P + ((size_t)b * kTT + t) * kD))[lane];
      float s = tanh_fast(p.x + c2v.x) * v2v.x + tanh_fast(p.y + c2v.y) * v2v.y +
                tanh_fast(p.z + c2v.z) * v2v.z + tanh_fast(p.w + c2v.w) * v2v.w;
      s += __shfl_xor(s, 1); s += __shfl_xor(s, 2); s += __shfl_xor(s, 4);
      s += __shfl_xor(s, 8); s += __shfl_xor(s, 16); s += __shfl_xor(s, 32);
      if (lane == 0) sc[(size_t)b * kTT + t] = s;
    }
  }
}

// softmax over 6135 (in-place -> alpha)
__global__ void k_sm2(float* sc) {
  int b = blockIdx.x, tid = threadIdx.x;
  __shared__ float red[4];
  float m = -1e30f;
  for (int t = tid; t < kTT; t += 256) m = fmaxf(m, sc[(size_t)b * kTT + t]);
#pragma unroll
  for (int o = 1; o < 64; o <<= 1) m = fmaxf(m, __shfl_xor(m, o));
  if ((tid & 63) == 0) red[tid >> 6] = m;
  __syncthreads();
  float mm = fmaxf(fmaxf(red[0], red[1]), fmaxf(red[2], red[3]));
  float s = 0.f;
  for (int t = tid; t < kTT; t += 256) s += __expf(sc[(size_t)b * kTT + t] - mm);
#pragma unroll
  for (int o = 1; o < 64; o <<= 1) s += __shfl_xor(s, o);
  __syncthreads();
  if ((tid & 63) == 0) red[tid >> 6] = s;
  __syncthreads();
  float inv = 1.f / (red[0] + red[1] + red[2] + red[3]);
  for (int t = tid; t < kTT; t += 256) sc[(size_t)b * kTT + t] = __expf(sc[(size_t)b * kTT + t] - mm) * inv;
}

// Ht partials: part[cc,b,d] = sum_t alpha * tanh(P + c2)
__global__ void k_aws(const float* sc, const float* P, const float* c2, float* part) {
  int cchunk = blockIdx.x, b = blockIdx.y, d = threadIdx.x;
  int tbeg = cchunk * 128;
  int tend = tbeg + 128; if (tend > kTT) tend = kTT;
  float c2d = c2[(size_t)b * kD + d];
  float acc = 0.f;
  for (int t = tbeg; t < tend; ++t)
    acc = fmaf(sc[(size_t)b * kTT + t], tanh_fast(P[((size_t)b * kTT + t) * kD + d] + c2d), acc);
  part[((size_t)cchunk * kB + b) * kD + d] = acc;
}

__global__ void k_ared(const float* part, float* Ht) {
  int b = blockIdx.x, d = threadIdx.x;
  float acc = 0.f;
  for (int cc = 0; cc < 48; ++cc) acc += part[((size_t)cc * kB + b) * kD + d];
  Ht[b * kD + d] = acc;
}

__global__ __launch_bounds__(1024) void k_cls(const float* Hf, const float* Ht,
                                              const float* w1, const float* b1,
                                              const float* w2, const float* b2, float* out) {
  int b = blockIdx.x, tid = threadIdx.x;
  __shared__ alignas(16) float hc[2 * kD];
  __shared__ alignas(16) float act[1024];
  if (tid < kD) hc[tid] = Hf[b * kD + tid];
  else if (tid < 2 * kD) hc[tid] = Ht[b * kD + tid - kD];
  __syncthreads();
  {
    float acc = b1[tid];
    const float4* wr = (const float4*)(w1 + (size_t)tid * 2 * kD);
    const float4* hr = (const float4*)hc;
    for (int i = 0; i < 128; ++i) {
      float4 wv = wr[i]; float4 hv = hr[i];
      acc += wv.x * hv.x + wv.y * hv.y + wv.z * hv.z + wv.w * hv.w;
    }
    act[tid] = acc > 0.f ? acc : 0.f;
  }
  __syncthreads();
  if (tid < kC) {
    float acc = b2[tid];
    const float4* wr = (const float4*)(w2 + (size_t)tid * 1024);
    const float4* ar = (const float4*)act;
    for (int i = 0; i < 256; ++i) {
      float4 wv = wr[i]; float4 av = ar[i];
      acc += wv.x * av.x + wv.y * av.y + wv.z * av.z + wv.w * av.w;
    }
    out[b * kC + tid] = acc;
  }
}

extern "C" void kernel_launch(void* const* d_in, const int* in_sizes, int n_in,
                              void* d_out, int out_size, void* d_ws, size_t ws_size,
                              hipStream_t stream) {
  (void)in_sizes; (void)n_in; (void)out_size;
  const int*   x     = (const int*)d_in[0];
  const int*   nodes = (const int*)d_in[2];
  const float* nmask = (const float*)d_in[3];
  const float* DDm   = (const float*)d_in[4];
  const float* DF    = (const float*)d_in[5];
  const float* wemb  = (const float*)d_in[6];
  const float* lemb  = (const float*)d_in[7];
  const float* eemb  = (const float*)d_in[8];
  const float* W1    = (const float*)d_in[9];
  const float* W2    = (const float*)d_in[10];
  const float* W3    = (const float*)d_in[11];
  const float* W4    = (const float*)d_in[12];
  const float* W6w   = (const float*)d_in[13];
  const float* W6bia = (const float*)d_in[14];
  const float* V1v   = (const float*)d_in[15];
  const float* V2v   = (const float*)d_in[16];
  const float* wih_f = (const float*)d_in[17];
  const float* whh_f = (const float*)d_in[18];
  const float* bih_f = (const float*)d_in[19];
  const float* bhh_f = (const float*)d_in[20];
  const float* wih_b = (const float*)d_in[21];
  const float* whh_b = (const float*)d_in[22];
  const float* bih_b = (const float*)d_in[23];
  const float* bhh_b = (const float*)d_in[24];
  const float* c1w   = (const float*)d_in[25];
  const float* c1b   = (const float*)d_in[26];
  const float* c2w   = (const float*)d_in[27];
  const float* c2b   = (const float*)d_in[28];
  const float* c3w   = (const float*)d_in[29];
  const float* c3b   = (const float*)d_in[30];
  const float* cls1w = (const float*)d_in[31];
  const float* cls1b = (const float*)d_in[32];
  const float* cls2w = (const float*)d_in[33];
  const float* cls2b = (const float*)d_in[34];
  float* out = (float*)d_out;
  float* ws  = (float*)d_ws;

  float* xe   = ws + OFF_XE;
  float* gi   = ws + OFF_GI;
  float* Fhat = ws + OFF_FHAT;
  float* UF   = ws + OFF_UF;
  float* effW = ws + OFF_EFFW;
  float* effB = ws + OFF_EFFB;
  float* w6at = ws + OFF_W6AT;
  float* w6bt = ws + OFF_W6BT;
  float* w1t  = ws + OFF_W1T;
  float* w2t  = ws + OFF_W2T;
  float* w3t  = ws + OFF_W3T;
  float* w4t  = ws + OFF_W4T;
  float* dhat = ws + OFF_DHAT;
  float* p1   = ws + OFF_P1;
  float* p2   = ws + OFF_P2;
  float* p3   = ws + OFF_P3;
  float* rs   = ws + OFF_RS;
  float* cs   = ws + OFF_CS;
  float* H1b  = ws + OFF_H1;
  float* c1bf = ws + OFF_C1;
  float* Hfb  = ws + OFF_HFv;
  float* c2bf = ws + OFF_C2;
  float* Htb  = ws + OFF_HT;
  float* scF  = ws + OFF_SCF;
  float* sc   = ws + OFF_SC;
  float* part = ws + OFF_PART;

  bool concurrent = ws_size >= TOTAL_CONCURRENT * sizeof(float);
  float* Pbuf = concurrent ? (ws + OFF_PBUF) : gi;   // fallback overlays gi (sequential only)

  // gather + input GEMM (critical path for GRU)
  k_xe<<<2048, 256, 0, stream>>>(x, wemb, xe);
  k_transpose<<<kD, kD, 0, stream>>>(w1t, W1, kD);
  k_transpose<<<kD, kD, 0, stream>>>(w2t, W2, kD);
  k_transpose<<<kD, kD, 0, stream>>>(w3t, W3, kD);
  k_transpose<<<kD, kD, 0, stream>>>(w4t, W4, kD);
  k_transpose<<<kD, kD, 0, stream>>>(w6at, W6w, 2 * kD);
  k_transpose<<<kD, kD, 0, stream>>>(w6bt, W6w + kD, 2 * kD);
  k_gemm_gi<<<dim3(512, 12), 256, 0, stream>>>(xe, wih_f, wih_b, bih_f, bih_b, gi);

  // graph branch (small)
  k_rowcol<<<1, kA, 0, stream>>>(DDm, rs, cs);
  k_proj3<<<kA, kD, 0, stream>>>(lemb, w1t, w2t, w3t, p1, p2, p3);
  k_dhat<<<kA, kD, 0, stream>>>(DDm, p1, p2, p3, rs, cs, dhat);
  k_fhat<<<dim3(16, kB), kD, 0, stream>>>(nodes, nmask, eemb, DF, w4t, dhat, Fhat);

  // folded conv weights
  k_fold<<<dim3(64, 12), kD, 0, stream>>>(c1w, c2w, c3w, w6at, effW);
  k_effb<<<3, kD, 0, stream>>>(c1b, c2b, c3b, w6at, effB);

  // fused GRU + conv
  if (concurrent) {
    k_main<<<kGruBlocks + kConvBlocks, 768, 0, stream>>>(
        gi, whh_f, whh_b, bhh_f, bhh_b, H1b, xe, effW, effB, Pbuf, 0);
  } else {
    k_main<<<kGruBlocks, 768, 0, stream>>>(
        gi, whh_f, whh_b, bhh_f, bhh_b, H1b, xe, effW, effB, Pbuf, 0);
    k_main<<<kConvBlocks, 768, 0, stream>>>(
        gi, whh_f, whh_b, bhh_f, bhh_b, H1b, xe, effW, effB, Pbuf, kGruBlocks);
  }

  // attn pool 1 over F_hat
  k_ctxproj<<<kB, kD, 0, stream>>>(H1b, w6bt, W6bia, c1bf);
  k_attn1<<<dim3(16, kB), kD, 0, stream>>>(Fhat, w6at, c1bf, V1v, UF, scF);
  k_attn1_fin<<<kB, kD, 0, stream>>>(scF, UF, Hfb);
  k_ctxproj<<<kB, kD, 0, stream>>>(Hfb, w6bt, W6bia, c2bf);

  // attn pool 2 over conv features (tanh applied on the fly) + classifier
  k_score<<<dim3(192, kB), 256, 0, stream>>>(Pbuf, c2bf, V2v, sc);
  k_sm2<<<kB, 256, 0, stream>>>(sc);
  k_aws<<<dim3(48, kB), kD, 0, stream>>>(sc, Pbuf, c2bf, part);
  k_ared<<<kB, kD, 0, stream>>>(part, Htb);
  k_cls<<<kB, 1024, 0, stream>>>(Hfb, Htb, cls1w, cls1b, cls2w, cls2b, out);
}